// Round 2
// baseline (992.685 us; speedup 1.0000x reference)
//
#include <hip/hip_runtime.h>
#include <hip/hip_fp16.h>

typedef __attribute__((ext_vector_type(8))) short short8;
typedef __attribute__((ext_vector_type(4))) short short4v;
typedef __attribute__((ext_vector_type(4))) float floatx4;
typedef _Float16 half8 __attribute__((ext_vector_type(8)));

static __device__ __forceinline__ short f2h(float f) {
    _Float16 h = (_Float16)f;
    return __builtin_bit_cast(short, h);
}

static __device__ __forceinline__ floatx4 mfma16(short8 a, short8 b, floatx4 c) {
    return __builtin_amdgcn_mfma_f32_16x16x32_f16(__builtin_bit_cast(half8, a),
                                                  __builtin_bit_cast(half8, b), c, 0, 0, 0);
}

static __device__ __forceinline__ void async16(const void* g, void* l) {
    __builtin_amdgcn_global_load_lds((const __attribute__((address_space(1))) void*)g,
                                     (__attribute__((address_space(3))) void*)l, 16, 0, 0);
}

// ---------------------------------------------------------------- LayerNorm -> fp16 hi/lo
__global__ __launch_bounds__(256) void ln_kernel(const float* __restrict__ x,
                                                 const float* __restrict__ gamma,
                                                 const float* __restrict__ beta,
                                                 short* __restrict__ xh, short* __restrict__ xl) {
    __shared__ float red[8];
    const int row = blockIdx.x, tid = threadIdx.x;
    const int w = tid >> 6, lane = tid & 63;
    const float4 v = ((const float4*)(x + (size_t)row * 1024))[tid];
    float s = v.x + v.y + v.z + v.w;
    float ss = v.x * v.x + v.y * v.y + v.z * v.z + v.w * v.w;
#pragma unroll
    for (int off = 32; off; off >>= 1) {
        s += __shfl_xor(s, off);
        ss += __shfl_xor(ss, off);
    }
    if (lane == 0) { red[w] = s; red[4 + w] = ss; }
    __syncthreads();
    s = red[0] + red[1] + red[2] + red[3];
    ss = red[4] + red[5] + red[6] + red[7];
    const float mu = s * (1.f / 1024.f);
    const float rs = rsqrtf(ss * (1.f / 1024.f) - mu * mu + 1e-5f);
    const float4 g = ((const float4*)gamma)[tid];
    const float4 bt = ((const float4*)beta)[tid];
    float y[4];
    y[0] = (v.x - mu) * rs * g.x + bt.x;
    y[1] = (v.y - mu) * rs * g.y + bt.y;
    y[2] = (v.z - mu) * rs * g.z + bt.z;
    y[3] = (v.w - mu) * rs * g.w + bt.w;
    short4v ph, pl;
#pragma unroll
    for (int i = 0; i < 4; i++) {
        _Float16 h = (_Float16)y[i];
        ph[i] = __builtin_bit_cast(short, h);
        pl[i] = f2h(y[i] - (float)h);
    }
    *(short4v*)(xh + (size_t)row * 1024 + tid * 4) = ph;
    *(short4v*)(xl + (size_t)row * 1024 + tid * 4) = pl;
}

// ------------------------------------------------- transpose + cast fp32 -> fp16 (hi/lo)
__global__ void tcast_split(const float* __restrict__ in, short* __restrict__ outH,
                            short* __restrict__ outL, int R, int C) {
    __shared__ float t[32][33];
    const int bx = blockIdx.x * 32, by = blockIdx.y * 32;
    const int tx = threadIdx.x, ty = threadIdx.y;
#pragma unroll
    for (int i = 0; i < 32; i += 8) t[ty + i][tx] = in[(size_t)(by + ty + i) * C + bx + tx];
    __syncthreads();
#pragma unroll
    for (int i = 0; i < 32; i += 8) {
        float v = t[tx][ty + i];
        _Float16 h = (_Float16)v;
        outH[(size_t)(bx + ty + i) * R + by + tx] = __builtin_bit_cast(short, h);
        outL[(size_t)(bx + ty + i) * R + by + tx] = f2h(v - (float)h);
    }
}

__global__ void tcast_h(const float* __restrict__ in, short* __restrict__ out, int R, int C) {
    __shared__ float t[32][33];
    const int bx = blockIdx.x * 32, by = blockIdx.y * 32;
    const int tx = threadIdx.x, ty = threadIdx.y;
#pragma unroll
    for (int i = 0; i < 32; i += 8) t[ty + i][tx] = in[(size_t)(by + ty + i) * C + bx + tx];
    __syncthreads();
#pragma unroll
    for (int i = 0; i < 32; i += 8) out[(size_t)(bx + ty + i) * R + by + tx] = f2h(t[tx][ty + i]);
}

// ---------------------------------------------------------------- QKV GEMM, fp16 3-term split
// C = (Ah+Al)*(Bh+Bl)^T (drop Al*Bl). A: [8192][1024], BT: [3072][1024].
// Epilogue: RoPE on q/k (q *= 0.125), V written transposed [bh][d][n].
__global__ __launch_bounds__(256, 2) void gemm_qkv(const short* __restrict__ Ah,
                                                   const short* __restrict__ Al,
                                                   const short* __restrict__ Bh,
                                                   const short* __restrict__ Bl,
                                                   short* __restrict__ Qd, short* __restrict__ Kd,
                                                   short* __restrict__ VTb) {
    __shared__ __align__(16) short sAh[128 * 32];
    __shared__ __align__(16) short sAl[128 * 32];
    __shared__ __align__(16) short sBh[128 * 32];
    __shared__ __align__(16) short sBl[128 * 32];
    const int tid = threadIdx.x;
    const int w = tid >> 6, lane = tid & 63, quad = lane >> 4, l15 = lane & 15;
    const int wm = w >> 1, wn = w & 1;
    const int m0 = blockIdx.y * 128, n0 = blockIdx.x * 128;

    floatx4 acc[4][4];
#pragma unroll
    for (int i = 0; i < 4; i++)
#pragma unroll
        for (int j = 0; j < 4; j++) acc[i][j] = (floatx4){0.f, 0.f, 0.f, 0.f};

    for (int k0 = 0; k0 < 1024; k0 += 32) {
        __syncthreads();
#pragma unroll
        for (int i = 0; i < 2; ++i) {
            int c = i * 256 + tid;
            int r = c >> 2, kc = (c & 3) << 3;
            const size_t ga = (size_t)(m0 + r) * 1024 + k0 + kc;
            const size_t gb = (size_t)(n0 + r) * 1024 + k0 + kc;
            async16(Ah + ga, (char*)sAh + c * 16);
            async16(Al + ga, (char*)sAl + c * 16);
            async16(Bh + gb, (char*)sBh + c * 16);
            async16(Bl + gb, (char*)sBl + c * 16);
        }
        __syncthreads();
        short8 ah[4], al[4], bh[4], bl[4];
#pragma unroll
        for (int t = 0; t < 4; t++) {
            const int ra = (wm * 64 + t * 16 + l15) * 32 + quad * 8;
            const int rb = (wn * 64 + t * 16 + l15) * 32 + quad * 8;
            ah[t] = *(const short8*)(sAh + ra);
            al[t] = *(const short8*)(sAl + ra);
            bh[t] = *(const short8*)(sBh + rb);
            bl[t] = *(const short8*)(sBl + rb);
        }
#pragma unroll
        for (int tm = 0; tm < 4; tm++)
#pragma unroll
            for (int tn = 0; tn < 4; tn++) {
                acc[tm][tn] = mfma16(ah[tm], bh[tn], acc[tm][tn]);
                acc[tm][tn] = mfma16(ah[tm], bl[tn], acc[tm][tn]);
                acc[tm][tn] = mfma16(al[tm], bh[tn], acc[tm][tn]);
            }
    }

#pragma unroll
    for (int tn = 0; tn < 4; tn++) {
        const int col = n0 + wn * 64 + tn * 16 + l15;
#pragma unroll
        for (int tm = 0; tm < 4; tm++) {
            const int row0 = m0 + wm * 64 + tm * 16 + quad * 4;
            const int mat = col >> 10, cm = col & 1023, h = cm >> 6, d = cm & 63;
            const int b = row0 >> 11, nn = row0 & 2047;
            const int bh2 = b * 16 + h;
            if (mat == 2) {
                short4v pk;
#pragma unroll
                for (int i = 0; i < 4; i++) pk[i] = f2h(acc[tm][tn][i]);
                *(short4v*)(VTb + (size_t)(bh2 * 64 + d) * 2048 + nn) = pk;
            } else {
                // inv = 10000^(-(d>>1)/32);  log2(10000)/32 = 0.4152410118609203
                const float inv = exp2f((float)(d >> 1) * -0.4152410118609203f);
                short* dst = (mat == 0) ? Qd : Kd;
                const float qs = (mat == 0) ? 0.125f : 1.0f;
#pragma unroll
                for (int i = 0; i < 4; i++) {
                    float v = acc[tm][tn][i];
                    float pv = __shfl_xor(v, 1);  // partner within (even,odd) column pair
                    float ang = (float)(nn + i) * inv;
                    float sn, cs;
                    sincosf(ang, &sn, &cs);
                    float r = (d & 1) ? (pv * sn + v * cs) : (v * cs - pv * sn);
                    dst[(size_t)(bh2 * 2048 + nn + i) * 64 + d] = f2h(r * qs);
                }
            }
        }
    }
}

// ---------------------------------------------------------------- out-proj GEMM (plain fp16)
__global__ __launch_bounds__(256, 2) void gemm_out(const short* __restrict__ A,
                                                   const short* __restrict__ BT,
                                                   float* __restrict__ Fout,
                                                   const float* __restrict__ bias) {
    __shared__ __align__(16) short sA[128 * 32];
    __shared__ __align__(16) short sB[128 * 32];
    const int tid = threadIdx.x;
    const int w = tid >> 6, lane = tid & 63, quad = lane >> 4, l15 = lane & 15;
    const int wm = w >> 1, wn = w & 1;
    const int m0 = blockIdx.y * 128, n0 = blockIdx.x * 128;

    floatx4 acc[4][4];
#pragma unroll
    for (int i = 0; i < 4; i++)
#pragma unroll
        for (int j = 0; j < 4; j++) acc[i][j] = (floatx4){0.f, 0.f, 0.f, 0.f};

    for (int k0 = 0; k0 < 1024; k0 += 32) {
        __syncthreads();
#pragma unroll
        for (int i = 0; i < 2; ++i) {
            int c = i * 256 + tid;
            int r = c >> 2, kc = (c & 3) << 3;
            async16(A + (size_t)(m0 + r) * 1024 + k0 + kc, (char*)sA + c * 16);
            async16(BT + (size_t)(n0 + r) * 1024 + k0 + kc, (char*)sB + c * 16);
        }
        __syncthreads();
        short8 af[4], bf[4];
#pragma unroll
        for (int t = 0; t < 4; t++) af[t] = *(const short8*)(sA + (wm * 64 + t * 16 + l15) * 32 + quad * 8);
#pragma unroll
        for (int t = 0; t < 4; t++) bf[t] = *(const short8*)(sB + (wn * 64 + t * 16 + l15) * 32 + quad * 8);
#pragma unroll
        for (int tm = 0; tm < 4; tm++)
#pragma unroll
            for (int tn = 0; tn < 4; tn++) acc[tm][tn] = mfma16(af[tm], bf[tn], acc[tm][tn]);
    }

#pragma unroll
    for (int tn = 0; tn < 4; tn++) {
        const int col = n0 + wn * 64 + tn * 16 + l15;
        const float bb = bias[col];
#pragma unroll
        for (int tm = 0; tm < 4; tm++) {
            const int row0 = m0 + wm * 64 + tm * 16 + quad * 4;
#pragma unroll
            for (int i = 0; i < 4; i++) Fout[(size_t)(row0 + i) * 1024 + col] = acc[tm][tn][i] + bb;
        }
    }
}

// ---------------------------------------------------------------- attention (flash, fp16)
// Q (roped, pre-scaled) [bh][n][64], K [bh][n][64], VT [bh][64][n]; out [b][n][h*64+d] fp16
__global__ __launch_bounds__(256, 2) void attn_kernel(const short* __restrict__ Qg,
                                                      const short* __restrict__ Kg,
                                                      const short* __restrict__ VTg,
                                                      short* __restrict__ Og) {
    __shared__ __align__(16) short sVT[64 * 136];   // V^T tile, stride 136
    __shared__ __align__(16) short sKP[128 * 136];  // phase 1: K tile stride 72; phase 2: P stride 136

    const int tid = threadIdx.x;
    const int w = tid >> 6, lane = tid & 63, quad = lane >> 4, l15 = lane & 15;
    const int qt = blockIdx.x, bh = blockIdx.y;
    const float LOG2E = 1.4426950408889634f;
    const int srcl = (l15 >> 2) << 4;  // wave-lane holding row-(l15) softmax stats (element l15&3)

    const short* Qp = Qg + (size_t)(bh * 2048 + qt * 128) * 64;
    const short* Kp = Kg + (size_t)bh * 2048 * 64;
    const short* Vp = VTg + (size_t)bh * 64 * 2048;

    short8 aq[2][2];
#pragma unroll
    for (int tq = 0; tq < 2; tq++)
#pragma unroll
        for (int kh = 0; kh < 2; kh++)
            aq[tq][kh] = *(const short8*)(Qp + (w * 32 + tq * 16 + l15) * 64 + kh * 32 + quad * 8);

    floatx4 o[4][2];
#pragma unroll
    for (int i = 0; i < 4; i++)
#pragma unroll
        for (int j = 0; j < 2; j++) o[i][j] = (floatx4){0.f, 0.f, 0.f, 0.f};
    float m_run[2][4], l_run[2][4];
#pragma unroll
    for (int tq = 0; tq < 2; tq++)
#pragma unroll
        for (int i = 0; i < 4; i++) { m_run[tq][i] = -1e30f; l_run[tq][i] = 0.f; }

    for (int kt = 0; kt < 16; ++kt) {
        const int n0 = kt * 128;
        __syncthreads();  // prior-iter P/VT reads done before restaging
#pragma unroll
        for (int i = 0; i < 4; ++i) {
            int c = i * 256 + tid;
            {
                int r = c >> 3, c8 = (c & 7) << 3;
                *(short8*)(sKP + r * 72 + c8) = *(const short8*)(Kp + (size_t)(n0 + r) * 64 + c8);
            }
            {
                int d = c >> 4, c16 = (c & 15) << 3;
                *(short8*)(sVT + d * 136 + c16) = *(const short8*)(Vp + (size_t)d * 2048 + n0 + c16);
            }
        }
        __syncthreads();

        floatx4 s[2][8];
#pragma unroll
        for (int tn = 0; tn < 8; tn++) {
            short8 b0 = *(const short8*)(sKP + (tn * 16 + l15) * 72 + quad * 8);
            short8 b1 = *(const short8*)(sKP + (tn * 16 + l15) * 72 + 32 + quad * 8);
#pragma unroll
            for (int tq = 0; tq < 2; tq++) {
                floatx4 z = (floatx4){0.f, 0.f, 0.f, 0.f};
                z = mfma16(aq[tq][0], b0, z);
                z = mfma16(aq[tq][1], b1, z);
                s[tq][tn] = z;
            }
        }
        __syncthreads();  // all K reads done before P overwrites sKP

        float alpha[2][4];
#pragma unroll
        for (int tq = 0; tq < 2; tq++)
#pragma unroll
            for (int i = 0; i < 4; i++) {
                float mx = s[tq][0][i];
#pragma unroll
                for (int tn = 1; tn < 8; tn++) mx = fmaxf(mx, s[tq][tn][i]);
                mx *= LOG2E;
#pragma unroll
                for (int off = 1; off < 16; off <<= 1) mx = fmaxf(mx, __shfl_xor(mx, off));
                float mn = fmaxf(m_run[tq][i], mx);
                alpha[tq][i] = exp2f(m_run[tq][i] - mn);
                m_run[tq][i] = mn;
            }
        float lsum[2][4];
#pragma unroll
        for (int tq = 0; tq < 2; tq++)
#pragma unroll
            for (int i = 0; i < 4; i++) lsum[tq][i] = 0.f;
#pragma unroll
        for (int tq = 0; tq < 2; tq++)
#pragma unroll
            for (int tn = 0; tn < 8; tn++)
#pragma unroll
                for (int i = 0; i < 4; i++) {
                    float p = exp2f(s[tq][tn][i] * LOG2E - m_run[tq][i]);
                    lsum[tq][i] += p;
                    sKP[(w * 32 + tq * 16 + quad * 4 + i) * 136 + tn * 16 + l15] = f2h(p);
                }
#pragma unroll
        for (int tq = 0; tq < 2; tq++)
#pragma unroll
            for (int i = 0; i < 4; i++) {
                float ls = lsum[tq][i];
#pragma unroll
                for (int off = 1; off < 16; off <<= 1) ls += __shfl_xor(ls, off);
                l_run[tq][i] = l_run[tq][i] * alpha[tq][i] + ls;
            }
        // broadcast alpha (row-indexed, rows quad*4+i) to col-indexed lanes (row = l15):
        float av[2];
#pragma unroll
        for (int tq = 0; tq < 2; tq++) {
            float t0 = __shfl(alpha[tq][0], srcl), t1 = __shfl(alpha[tq][1], srcl);
            float t2 = __shfl(alpha[tq][2], srcl), t3 = __shfl(alpha[tq][3], srcl);
            float a01 = (l15 & 1) ? t1 : t0, a23 = (l15 & 1) ? t3 : t2;
            av[tq] = (l15 & 2) ? a23 : a01;
        }
#pragma unroll
        for (int dt = 0; dt < 4; dt++)
#pragma unroll
            for (int tq = 0; tq < 2; tq++) o[dt][tq] *= av[tq];
        __syncthreads();  // P (cross-lane in LDS) visible before PV reads

#pragma unroll
        for (int nc = 0; nc < 4; nc++) {
            short8 pa[4];
#pragma unroll
            for (int dt = 0; dt < 4; dt++)
                pa[dt] = *(const short8*)(sVT + (dt * 16 + l15) * 136 + nc * 32 + quad * 8);
            short8 pb[2];
#pragma unroll
            for (int tq = 0; tq < 2; tq++)
                pb[tq] = *(const short8*)(sKP + (w * 32 + tq * 16 + l15) * 136 + nc * 32 + quad * 8);
#pragma unroll
            for (int dt = 0; dt < 4; dt++)
#pragma unroll
                for (int tq = 0; tq < 2; tq++) o[dt][tq] = mfma16(pa[dt], pb[tq], o[dt][tq]);
        }
    }

    // broadcast l_run (row-indexed) to col-indexed lanes, register-only
    float linv[2];
#pragma unroll
    for (int tq = 0; tq < 2; tq++) {
        float t0 = __shfl(l_run[tq][0], srcl), t1 = __shfl(l_run[tq][1], srcl);
        float t2 = __shfl(l_run[tq][2], srcl), t3 = __shfl(l_run[tq][3], srcl);
        float a01 = (l15 & 1) ? t1 : t0, a23 = (l15 & 1) ? t3 : t2;
        linv[tq] = 1.0f / ((l15 & 2) ? a23 : a01);
    }
    const int b = bh >> 4, h = bh & 15;
#pragma unroll
    for (int dt = 0; dt < 4; dt++)
#pragma unroll
        for (int tq = 0; tq < 2; tq++) {
            int q = w * 32 + tq * 16 + l15;
            size_t rowg = (size_t)(b * 2048 + qt * 128 + q);
            int colg = h * 64 + dt * 16 + quad * 4;
            short4v pk;
#pragma unroll
            for (int i = 0; i < 4; i++) pk[i] = f2h(o[dt][tq][i] * linv[tq]);
            *(short4v*)(Og + rowg * 1024 + colg) = pk;
        }
}

// ---------------------------------------------------------------- launch
extern "C" void kernel_launch(void* const* d_in, const int* in_sizes, int n_in, void* d_out,
                              int out_size, void* d_ws, size_t ws_size, hipStream_t stream) {
    const float* x = (const float*)d_in[0];
    const float* gamma = (const float*)d_in[1];
    const float* beta = (const float*)d_in[2];
    const float* w_qkv = (const float*)d_in[3];
    const float* w_out = (const float*)d_in[4];
    const float* b_out = (const float*)d_in[5];
    float* out = (float*)d_out;

    char* ws = (char*)d_ws;
    // ws layout (bytes), total 62 MB:
    short* xh = (short*)ws;                   // [8192][1024] fp16 hi; later reused as attn out
    short* xl = (short*)(ws + 16777216);      // [8192][1024] fp16 lo
    short* wh = (short*)(ws + 33554432);      // [3072][1024] w_qkv^T hi
    short* wl = (short*)(ws + 39845888);      // [3072][1024] w_qkv^T lo
    short* woT = (short*)(ws + 46137344);     // [1024][1024] w_out^T
    short* VTb = (short*)(ws + 48234496);     // [64][64][2048] V^T
    // Q and K live in d_out (exactly 2 x 16.78 MB = 33.55 MB); final GEMM overwrites it.
    short* Qd = (short*)d_out;                // [64][2048][64]
    short* Kd = (short*)d_out + 8388608;      // [64][2048][64]

    ln_kernel<<<8192, 256, 0, stream>>>(x, gamma, beta, xh, xl);
    tcast_split<<<dim3(96, 32), dim3(32, 8), 0, stream>>>(w_qkv, wh, wl, 1024, 3072);
    tcast_h<<<dim3(32, 32), dim3(32, 8), 0, stream>>>(w_out, woT, 1024, 1024);
    gemm_qkv<<<dim3(24, 64), 256, 0, stream>>>(xh, xl, wh, wl, Qd, Kd, VTb);
    attn_kernel<<<dim3(16, 64), 256, 0, stream>>>(Qd, Kd, VTb, xh);
    gemm_out<<<dim3(8, 64), 256, 0, stream>>>(xh, woT, out, b_out);
}

// Round 3
// 482.679 us; speedup vs baseline: 2.0566x; 2.0566x over previous
//
#include <hip/hip_runtime.h>
#include <hip/hip_fp16.h>

typedef __attribute__((ext_vector_type(8))) short short8;
typedef __attribute__((ext_vector_type(4))) short short4v;
typedef __attribute__((ext_vector_type(4))) float floatx4;
typedef _Float16 half8 __attribute__((ext_vector_type(8)));

static __device__ __forceinline__ short f2h(float f) {
    _Float16 h = (_Float16)f;
    return __builtin_bit_cast(short, h);
}

static __device__ __forceinline__ floatx4 mfma16(short8 a, short8 b, floatx4 c) {
    return __builtin_amdgcn_mfma_f32_16x16x32_f16(__builtin_bit_cast(half8, a),
                                                  __builtin_bit_cast(half8, b), c, 0, 0, 0);
}

static __device__ __forceinline__ void async16(const void* g, void* l) {
    __builtin_amdgcn_global_load_lds((const __attribute__((address_space(1))) void*)g,
                                     (__attribute__((address_space(3))) void*)l, 16, 0, 0);
}

// ---------------------------------------------------------------- LayerNorm -> fp16 hi/lo
__global__ __launch_bounds__(256) void ln_kernel(const float* __restrict__ x,
                                                 const float* __restrict__ gamma,
                                                 const float* __restrict__ beta,
                                                 short* __restrict__ xh, short* __restrict__ xl) {
    __shared__ float red[8];
    const int row = blockIdx.x, tid = threadIdx.x;
    const int w = tid >> 6, lane = tid & 63;
    const float4 v = ((const float4*)(x + (size_t)row * 1024))[tid];
    float s = v.x + v.y + v.z + v.w;
    float ss = v.x * v.x + v.y * v.y + v.z * v.z + v.w * v.w;
#pragma unroll
    for (int off = 32; off; off >>= 1) {
        s += __shfl_xor(s, off);
        ss += __shfl_xor(ss, off);
    }
    if (lane == 0) { red[w] = s; red[4 + w] = ss; }
    __syncthreads();
    s = red[0] + red[1] + red[2] + red[3];
    ss = red[4] + red[5] + red[6] + red[7];
    const float mu = s * (1.f / 1024.f);
    const float rs = rsqrtf(ss * (1.f / 1024.f) - mu * mu + 1e-5f);
    const float4 g = ((const float4*)gamma)[tid];
    const float4 bt = ((const float4*)beta)[tid];
    float y[4];
    y[0] = (v.x - mu) * rs * g.x + bt.x;
    y[1] = (v.y - mu) * rs * g.y + bt.y;
    y[2] = (v.z - mu) * rs * g.z + bt.z;
    y[3] = (v.w - mu) * rs * g.w + bt.w;
    short4v ph, pl;
#pragma unroll
    for (int i = 0; i < 4; i++) {
        _Float16 h = (_Float16)y[i];
        ph[i] = __builtin_bit_cast(short, h);
        pl[i] = f2h(y[i] - (float)h);
    }
    *(short4v*)(xh + (size_t)row * 1024 + tid * 4) = ph;
    *(short4v*)(xl + (size_t)row * 1024 + tid * 4) = pl;
}

// ------------------------------------------------- transpose + cast fp32 -> fp16 (hi/lo)
__global__ void tcast_split(const float* __restrict__ in, short* __restrict__ outH,
                            short* __restrict__ outL, int R, int C) {
    __shared__ float t[32][33];
    const int bx = blockIdx.x * 32, by = blockIdx.y * 32;
    const int tx = threadIdx.x, ty = threadIdx.y;
#pragma unroll
    for (int i = 0; i < 32; i += 8) t[ty + i][tx] = in[(size_t)(by + ty + i) * C + bx + tx];
    __syncthreads();
#pragma unroll
    for (int i = 0; i < 32; i += 8) {
        float v = t[tx][ty + i];
        _Float16 h = (_Float16)v;
        outH[(size_t)(bx + ty + i) * R + by + tx] = __builtin_bit_cast(short, h);
        outL[(size_t)(bx + ty + i) * R + by + tx] = f2h(v - (float)h);
    }
}

__global__ void tcast_h(const float* __restrict__ in, short* __restrict__ out, int R, int C) {
    __shared__ float t[32][33];
    const int bx = blockIdx.x * 32, by = blockIdx.y * 32;
    const int tx = threadIdx.x, ty = threadIdx.y;
#pragma unroll
    for (int i = 0; i < 32; i += 8) t[ty + i][tx] = in[(size_t)(by + ty + i) * C + bx + tx];
    __syncthreads();
#pragma unroll
    for (int i = 0; i < 32; i += 8) out[(size_t)(bx + ty + i) * R + by + tx] = f2h(t[tx][ty + i]);
}

// ---------------------------------------------------------------- QKV GEMM
// C = (Ah+Al)*(Bh+Bl)^T (drop Al*Bl) for Q/K block-cols; plain Ah*Bh for V block-cols.
// A: [8192][1024] fp16 hi/lo, BT: [3072][1024] fp16 hi/lo.
// Epilogue: RoPE on q/k (q *= 0.125) -> Q/K [bh][n][64]; V transposed -> [bh][d][n].
// All HBM stores are LDS-staged, 16B/lane fully coalesced.
__global__ __launch_bounds__(256, 2) void gemm_qkv(const short* __restrict__ Ah,
                                                   const short* __restrict__ Al,
                                                   const short* __restrict__ Bh,
                                                   const short* __restrict__ Bl,
                                                   short* __restrict__ Qd, short* __restrict__ Kd,
                                                   short* __restrict__ VTb) {
    extern __shared__ __align__(16) short pool[];  // 34816 B
    short* sAh = pool;          // 128*32
    short* sAl = pool + 4096;   // 128*32
    short* sBh = pool + 8192;   // 128*32
    short* sBl = pool + 12288;  // 128*32
    short* sOut = pool;         // alias: [128][136] output tile (after barrier)

    const int tid = threadIdx.x;
    const int w = tid >> 6, lane = tid & 63, quad = lane >> 4, l15 = lane & 15;
    const int wm = w >> 1, wn = w & 1;
    const int m0 = blockIdx.y * 128, n0 = blockIdx.x * 128;
    const bool isV = (n0 >= 2048);

    floatx4 acc[4][4];
#pragma unroll
    for (int i = 0; i < 4; i++)
#pragma unroll
        for (int j = 0; j < 4; j++) acc[i][j] = (floatx4){0.f, 0.f, 0.f, 0.f};

    for (int k0 = 0; k0 < 1024; k0 += 32) {
        __syncthreads();
#pragma unroll
        for (int i = 0; i < 2; ++i) {
            int c = i * 256 + tid;
            int r = c >> 2, kc = (c & 3) << 3;
            const size_t ga = (size_t)(m0 + r) * 1024 + k0 + kc;
            const size_t gb = (size_t)(n0 + r) * 1024 + k0 + kc;
            async16(Ah + ga, (char*)sAh + c * 16);
            async16(Bh + gb, (char*)sBh + c * 16);
            if (!isV) {
                async16(Al + ga, (char*)sAl + c * 16);
                async16(Bl + gb, (char*)sBl + c * 16);
            }
        }
        __syncthreads();
        short8 ah[4], bh[4];
#pragma unroll
        for (int t = 0; t < 4; t++) {
            ah[t] = *(const short8*)(sAh + (wm * 64 + t * 16 + l15) * 32 + quad * 8);
            bh[t] = *(const short8*)(sBh + (wn * 64 + t * 16 + l15) * 32 + quad * 8);
        }
        if (!isV) {
            short8 al[4], bl[4];
#pragma unroll
            for (int t = 0; t < 4; t++) {
                al[t] = *(const short8*)(sAl + (wm * 64 + t * 16 + l15) * 32 + quad * 8);
                bl[t] = *(const short8*)(sBl + (wn * 64 + t * 16 + l15) * 32 + quad * 8);
            }
#pragma unroll
            for (int tm = 0; tm < 4; tm++)
#pragma unroll
                for (int tn = 0; tn < 4; tn++) {
                    acc[tm][tn] = mfma16(ah[tm], bh[tn], acc[tm][tn]);
                    acc[tm][tn] = mfma16(ah[tm], bl[tn], acc[tm][tn]);
                    acc[tm][tn] = mfma16(al[tm], bh[tn], acc[tm][tn]);
                }
        } else {
#pragma unroll
            for (int tm = 0; tm < 4; tm++)
#pragma unroll
                for (int tn = 0; tn < 4; tn++) acc[tm][tn] = mfma16(ah[tm], bh[tn], acc[tm][tn]);
        }
    }

    __syncthreads();  // all LDS staging reads done; pool becomes sOut

    const int b = m0 >> 11, nnb = m0 & 2047;
    if (!isV) {
        const float qs = (n0 < 1024) ? 0.125f : 1.0f;
#pragma unroll
        for (int tn = 0; tn < 4; tn++) {
            const int d = tn * 16 + l15;  // exact d: n0,wn*64 are multiples of 64
            const int colL = wn * 64 + tn * 16 + l15;
            const float inv = exp2f((float)(d >> 1) * -0.4152410118609203f);
#pragma unroll
            for (int tm = 0; tm < 4; tm++) {
                const int rowL = wm * 64 + tm * 16 + quad * 4;
#pragma unroll
                for (int i = 0; i < 4; i++) {
                    float v = acc[tm][tn][i];
                    float pv = __shfl_xor(v, 1);  // (even,odd) column pair partner
                    float ang = (float)(nnb + rowL + i) * inv;
                    float sn = __sinf(ang), cs = __cosf(ang);
                    float r = (d & 1) ? (pv * sn + v * cs) : (v * cs - pv * sn);
                    sOut[(rowL + i) * 136 + colL] = f2h(r * qs);
                }
            }
        }
        __syncthreads();
        short* dst0 = (n0 < 1024) ? Qd : Kd;
        const int hbase = (n0 & 1023) >> 6;
#pragma unroll
        for (int it = 0; it < 8; ++it) {
            int c = it * 256 + tid;
            int r = c >> 4, cg = (c & 15) * 8;
            int h = hbase + (cg >> 6), d = cg & 63;
            *(short8*)(dst0 + ((size_t)((b * 16 + h) * 2048 + nnb + r)) * 64 + d) =
                *(const short8*)(sOut + r * 136 + cg);
        }
    } else {
#pragma unroll
        for (int tn = 0; tn < 4; tn++) {
            const int colL = wn * 64 + tn * 16 + l15;
#pragma unroll
            for (int tm = 0; tm < 4; tm++) {
                const int rowL = wm * 64 + tm * 16 + quad * 4;
#pragma unroll
                for (int i = 0; i < 4; i++)
                    sOut[colL * 136 + rowL + i] = f2h(acc[tm][tn][i]);  // transposed tile
            }
        }
        __syncthreads();
        const int hbase = (n0 & 1023) >> 6;
#pragma unroll
        for (int it = 0; it < 8; ++it) {
            int c = it * 256 + tid;
            int ci = c >> 4, rg = (c & 15) * 8;
            int h = hbase + (ci >> 6), d = ci & 63;
            *(short8*)(VTb + ((size_t)((b * 16 + h) * 64 + d)) * 2048 + nnb + rg) =
                *(const short8*)(sOut + ci * 136 + rg);
        }
    }
}

// ---------------------------------------------------------------- out-proj GEMM (plain fp16)
__global__ __launch_bounds__(256, 2) void gemm_out(const short* __restrict__ A,
                                                   const short* __restrict__ BT,
                                                   float* __restrict__ Fout,
                                                   const float* __restrict__ bias) {
    __shared__ __align__(16) short sA[128 * 32];
    __shared__ __align__(16) short sB[128 * 32];
    const int tid = threadIdx.x;
    const int w = tid >> 6, lane = tid & 63, quad = lane >> 4, l15 = lane & 15;
    const int wm = w >> 1, wn = w & 1;
    const int m0 = blockIdx.y * 128, n0 = blockIdx.x * 128;

    floatx4 acc[4][4];
#pragma unroll
    for (int i = 0; i < 4; i++)
#pragma unroll
        for (int j = 0; j < 4; j++) acc[i][j] = (floatx4){0.f, 0.f, 0.f, 0.f};

    for (int k0 = 0; k0 < 1024; k0 += 32) {
        __syncthreads();
#pragma unroll
        for (int i = 0; i < 2; ++i) {
            int c = i * 256 + tid;
            int r = c >> 2, kc = (c & 3) << 3;
            async16(A + (size_t)(m0 + r) * 1024 + k0 + kc, (char*)sA + c * 16);
            async16(BT + (size_t)(n0 + r) * 1024 + k0 + kc, (char*)sB + c * 16);
        }
        __syncthreads();
        short8 af[4], bf[4];
#pragma unroll
        for (int t = 0; t < 4; t++) af[t] = *(const short8*)(sA + (wm * 64 + t * 16 + l15) * 32 + quad * 8);
#pragma unroll
        for (int t = 0; t < 4; t++) bf[t] = *(const short8*)(sB + (wn * 64 + t * 16 + l15) * 32 + quad * 8);
#pragma unroll
        for (int tm = 0; tm < 4; tm++)
#pragma unroll
            for (int tn = 0; tn < 4; tn++) acc[tm][tn] = mfma16(af[tm], bf[tn], acc[tm][tn]);
    }

    // fp32 stores: 16 lanes x 4 B = full 64 B lines per quad, already coalesced
#pragma unroll
    for (int tn = 0; tn < 4; tn++) {
        const int col = n0 + wn * 64 + tn * 16 + l15;
        const float bb = bias[col];
#pragma unroll
        for (int tm = 0; tm < 4; tm++) {
            const int row0 = m0 + wm * 64 + tm * 16 + quad * 4;
#pragma unroll
            for (int i = 0; i < 4; i++) Fout[(size_t)(row0 + i) * 1024 + col] = acc[tm][tn][i] + bb;
        }
    }
}

// ---------------------------------------------------------------- attention (flash, fp16)
// Q (roped, pre-scaled) [bh][n][64], K [bh][n][64], VT [bh][64][n]; out [b][n][h*64+d] fp16
__global__ __launch_bounds__(256, 2) void attn_kernel(const short* __restrict__ Qg,
                                                      const short* __restrict__ Kg,
                                                      const short* __restrict__ VTg,
                                                      short* __restrict__ Og) {
    __shared__ __align__(16) short sVT[64 * 136];   // V^T tile, stride 136
    __shared__ __align__(16) short sKP[128 * 136];  // K tile (stride 72) / P tile (stride 136) / out tile (stride 72)

    const int tid = threadIdx.x;
    const int w = tid >> 6, lane = tid & 63, quad = lane >> 4, l15 = lane & 15;
    const int qt = blockIdx.x, bh = blockIdx.y;
    const float LOG2E = 1.4426950408889634f;
    const int srcl = (l15 >> 2) << 4;  // wave-lane holding row-(l15) softmax stats

    const short* Qp = Qg + (size_t)(bh * 2048 + qt * 128) * 64;
    const short* Kp = Kg + (size_t)bh * 2048 * 64;
    const short* Vp = VTg + (size_t)bh * 64 * 2048;

    short8 aq[2][2];
#pragma unroll
    for (int tq = 0; tq < 2; tq++)
#pragma unroll
        for (int kh = 0; kh < 2; kh++)
            aq[tq][kh] = *(const short8*)(Qp + (w * 32 + tq * 16 + l15) * 64 + kh * 32 + quad * 8);

    floatx4 o[4][2];
#pragma unroll
    for (int i = 0; i < 4; i++)
#pragma unroll
        for (int j = 0; j < 2; j++) o[i][j] = (floatx4){0.f, 0.f, 0.f, 0.f};
    float m_run[2][4], l_run[2][4];
#pragma unroll
    for (int tq = 0; tq < 2; tq++)
#pragma unroll
        for (int i = 0; i < 4; i++) { m_run[tq][i] = -1e30f; l_run[tq][i] = 0.f; }

    for (int kt = 0; kt < 16; ++kt) {
        const int n0 = kt * 128;
        __syncthreads();  // prior-iter P/VT reads done before restaging
#pragma unroll
        for (int i = 0; i < 4; ++i) {
            int c = i * 256 + tid;
            {
                int r = c >> 3, c8 = (c & 7) << 3;
                *(short8*)(sKP + r * 72 + c8) = *(const short8*)(Kp + (size_t)(n0 + r) * 64 + c8);
            }
            {
                int d = c >> 4, c16 = (c & 15) << 3;
                *(short8*)(sVT + d * 136 + c16) = *(const short8*)(Vp + (size_t)d * 2048 + n0 + c16);
            }
        }
        __syncthreads();

        floatx4 s[2][8];
#pragma unroll
        for (int tn = 0; tn < 8; tn++) {
            short8 b0 = *(const short8*)(sKP + (tn * 16 + l15) * 72 + quad * 8);
            short8 b1 = *(const short8*)(sKP + (tn * 16 + l15) * 72 + 32 + quad * 8);
#pragma unroll
            for (int tq = 0; tq < 2; tq++) {
                floatx4 z = (floatx4){0.f, 0.f, 0.f, 0.f};
                z = mfma16(aq[tq][0], b0, z);
                z = mfma16(aq[tq][1], b1, z);
                s[tq][tn] = z;
            }
        }
        __syncthreads();  // all K reads done before P overwrites sKP

        float alpha[2][4];
#pragma unroll
        for (int tq = 0; tq < 2; tq++)
#pragma unroll
            for (int i = 0; i < 4; i++) {
                float mx = s[tq][0][i];
#pragma unroll
                for (int tn = 1; tn < 8; tn++) mx = fmaxf(mx, s[tq][tn][i]);
                mx *= LOG2E;
#pragma unroll
                for (int off = 1; off < 16; off <<= 1) mx = fmaxf(mx, __shfl_xor(mx, off));
                float mn = fmaxf(m_run[tq][i], mx);
                alpha[tq][i] = exp2f(m_run[tq][i] - mn);
                m_run[tq][i] = mn;
            }
        float lsum[2][4];
#pragma unroll
        for (int tq = 0; tq < 2; tq++)
#pragma unroll
            for (int i = 0; i < 4; i++) lsum[tq][i] = 0.f;
#pragma unroll
        for (int tq = 0; tq < 2; tq++)
#pragma unroll
            for (int tn = 0; tn < 8; tn++)
#pragma unroll
                for (int i = 0; i < 4; i++) {
                    float p = exp2f(s[tq][tn][i] * LOG2E - m_run[tq][i]);
                    lsum[tq][i] += p;
                    sKP[(w * 32 + tq * 16 + quad * 4 + i) * 136 + tn * 16 + l15] = f2h(p);
                }
#pragma unroll
        for (int tq = 0; tq < 2; tq++)
#pragma unroll
            for (int i = 0; i < 4; i++) {
                float ls = lsum[tq][i];
#pragma unroll
                for (int off = 1; off < 16; off <<= 1) ls += __shfl_xor(ls, off);
                l_run[tq][i] = l_run[tq][i] * alpha[tq][i] + ls;
            }
        // broadcast alpha (row-indexed) to col-indexed lanes, register-only
        float av[2];
#pragma unroll
        for (int tq = 0; tq < 2; tq++) {
            float t0 = __shfl(alpha[tq][0], srcl), t1 = __shfl(alpha[tq][1], srcl);
            float t2 = __shfl(alpha[tq][2], srcl), t3 = __shfl(alpha[tq][3], srcl);
            float a01 = (l15 & 1) ? t1 : t0, a23 = (l15 & 1) ? t3 : t2;
            av[tq] = (l15 & 2) ? a23 : a01;
        }
#pragma unroll
        for (int dt = 0; dt < 4; dt++)
#pragma unroll
            for (int tq = 0; tq < 2; tq++) o[dt][tq] *= av[tq];
        __syncthreads();  // P visible before PV reads

#pragma unroll
        for (int nc = 0; nc < 4; nc++) {
            short8 pa[4];
#pragma unroll
            for (int dt = 0; dt < 4; dt++)
                pa[dt] = *(const short8*)(sVT + (dt * 16 + l15) * 136 + nc * 32 + quad * 8);
            short8 pb[2];
#pragma unroll
            for (int tq = 0; tq < 2; tq++)
                pb[tq] = *(const short8*)(sKP + (w * 32 + tq * 16 + l15) * 136 + nc * 32 + quad * 8);
#pragma unroll
            for (int dt = 0; dt < 4; dt++)
#pragma unroll
                for (int tq = 0; tq < 2; tq++) o[dt][tq] = mfma16(pa[dt], pb[tq], o[dt][tq]);
        }
    }

    // broadcast l_run to col-indexed lanes
    float linv[2];
#pragma unroll
    for (int tq = 0; tq < 2; tq++) {
        float t0 = __shfl(l_run[tq][0], srcl), t1 = __shfl(l_run[tq][1], srcl);
        float t2 = __shfl(l_run[tq][2], srcl), t3 = __shfl(l_run[tq][3], srcl);
        float a01 = (l15 & 1) ? t1 : t0, a23 = (l15 & 1) ? t3 : t2;
        linv[tq] = 1.0f / ((l15 & 2) ? a23 : a01);
    }

    // stage output tile [128 q][64 d] in LDS (stride 72), then coalesced 16B stores
    __syncthreads();  // last PV reads of sKP done
#pragma unroll
    for (int dt = 0; dt < 4; dt++)
#pragma unroll
        for (int tq = 0; tq < 2; tq++) {
            int q = w * 32 + tq * 16 + l15;
            int d0 = dt * 16 + quad * 4;
            short4v pk;
#pragma unroll
            for (int i = 0; i < 4; i++) pk[i] = f2h(o[dt][tq][i] * linv[tq]);
            *(short4v*)(sKP + q * 72 + d0) = pk;
        }
    __syncthreads();
    const int b = bh >> 4, h = bh & 15;
#pragma unroll
    for (int it = 0; it < 4; ++it) {
        int c = it * 256 + tid;
        int r = c >> 3, dg = (c & 7) * 8;
        *(short8*)(Og + (size_t)(b * 2048 + qt * 128 + r) * 1024 + h * 64 + dg) =
            *(const short8*)(sKP + r * 72 + dg);
    }
}

// ---------------------------------------------------------------- launch
extern "C" void kernel_launch(void* const* d_in, const int* in_sizes, int n_in, void* d_out,
                              int out_size, void* d_ws, size_t ws_size, hipStream_t stream) {
    const float* x = (const float*)d_in[0];
    const float* gamma = (const float*)d_in[1];
    const float* beta = (const float*)d_in[2];
    const float* w_qkv = (const float*)d_in[3];
    const float* w_out = (const float*)d_in[4];
    const float* b_out = (const float*)d_in[5];
    float* out = (float*)d_out;

    char* ws = (char*)d_ws;
    short* xh = (short*)ws;                   // [8192][1024] fp16 hi; later reused as attn out
    short* xl = (short*)(ws + 16777216);      // [8192][1024] fp16 lo
    short* wh = (short*)(ws + 33554432);      // [3072][1024] w_qkv^T hi
    short* wl = (short*)(ws + 39845888);      // [3072][1024] w_qkv^T lo
    short* woT = (short*)(ws + 46137344);     // [1024][1024] w_out^T
    short* VTb = (short*)(ws + 48234496);     // [64][64][2048] V^T
    // Q and K live in d_out (2 x 16.78 MB); final GEMM overwrites it.
    short* Qd = (short*)d_out;                // [64][2048][64]
    short* Kd = (short*)d_out + 8388608;      // [64][2048][64]

    ln_kernel<<<8192, 256, 0, stream>>>(x, gamma, beta, xh, xl);
    tcast_split<<<dim3(96, 32), dim3(32, 8), 0, stream>>>(w_qkv, wh, wl, 1024, 3072);
    tcast_h<<<dim3(32, 32), dim3(32, 8), 0, stream>>>(w_out, woT, 1024, 1024);
    gemm_qkv<<<dim3(24, 64), 256, 34816, stream>>>(xh, xl, wh, wl, Qd, Kd, VTb);
    attn_kernel<<<dim3(16, 64), 256, 0, stream>>>(Qd, Kd, VTb, xh);
    gemm_out<<<dim3(8, 64), 256, 0, stream>>>(xh, woT, out, b_out);
}

// Round 4
// 408.251 us; speedup vs baseline: 2.4316x; 1.1823x over previous
//
#include <hip/hip_runtime.h>
#include <hip/hip_fp16.h>

typedef __attribute__((ext_vector_type(8))) short short8;
typedef __attribute__((ext_vector_type(4))) short short4v;
typedef __attribute__((ext_vector_type(4))) float floatx4;
typedef _Float16 half8 __attribute__((ext_vector_type(8)));

static __device__ __forceinline__ short f2h(float f) {
    _Float16 h = (_Float16)f;
    return __builtin_bit_cast(short, h);
}

static __device__ __forceinline__ floatx4 mfma16(short8 a, short8 b, floatx4 c) {
    return __builtin_amdgcn_mfma_f32_16x16x32_f16(__builtin_bit_cast(half8, a),
                                                  __builtin_bit_cast(half8, b), c, 0, 0, 0);
}

static __device__ __forceinline__ void async16(const void* g, void* l) {
    __builtin_amdgcn_global_load_lds((const __attribute__((address_space(1))) void*)g,
                                     (__attribute__((address_space(3))) void*)l, 16, 0, 0);
}

// ---------------------------------------------------------------- LayerNorm -> fp16
__global__ __launch_bounds__(256) void ln_kernel(const float* __restrict__ x,
                                                 const float* __restrict__ gamma,
                                                 const float* __restrict__ beta,
                                                 short* __restrict__ xh) {
    __shared__ float red[8];
    const int row = blockIdx.x, tid = threadIdx.x;
    const int w = tid >> 6, lane = tid & 63;
    const float4 v = ((const float4*)(x + (size_t)row * 1024))[tid];
    float s = v.x + v.y + v.z + v.w;
    float ss = v.x * v.x + v.y * v.y + v.z * v.z + v.w * v.w;
#pragma unroll
    for (int off = 32; off; off >>= 1) {
        s += __shfl_xor(s, off);
        ss += __shfl_xor(ss, off);
    }
    if (lane == 0) { red[w] = s; red[4 + w] = ss; }
    __syncthreads();
    s = red[0] + red[1] + red[2] + red[3];
    ss = red[4] + red[5] + red[6] + red[7];
    const float mu = s * (1.f / 1024.f);
    const float rs = rsqrtf(ss * (1.f / 1024.f) - mu * mu + 1e-5f);
    const float4 g = ((const float4*)gamma)[tid];
    const float4 bt = ((const float4*)beta)[tid];
    short4v ph;
    ph[0] = f2h((v.x - mu) * rs * g.x + bt.x);
    ph[1] = f2h((v.y - mu) * rs * g.y + bt.y);
    ph[2] = f2h((v.z - mu) * rs * g.z + bt.z);
    ph[3] = f2h((v.w - mu) * rs * g.w + bt.w);
    *(short4v*)(xh + (size_t)row * 1024 + tid * 4) = ph;
}

// ------------------------------------------------- transpose + cast fp32 -> fp16
__global__ void tcast_h(const float* __restrict__ in, short* __restrict__ out, int R, int C) {
    __shared__ float t[32][33];
    const int bx = blockIdx.x * 32, by = blockIdx.y * 32;
    const int tx = threadIdx.x, ty = threadIdx.y;
#pragma unroll
    for (int i = 0; i < 32; i += 8) t[ty + i][tx] = in[(size_t)(by + ty + i) * C + bx + tx];
    __syncthreads();
#pragma unroll
    for (int i = 0; i < 32; i += 8) out[(size_t)(bx + ty + i) * R + by + tx] = f2h(t[tx][ty + i]);
}

// ---------------------------------------------------------------- QKV GEMM (plain fp16)
// C = A * BT^T. A: [8192][1024], BT: [3072][1024].
// Epilogue: RoPE on q/k; Q scaled by 0.125*log2(e) (log2-domain softmax downstream);
// Q/K -> [bh][n][64]; V transposed -> [bh][d][n]. LDS-staged coalesced stores.
__global__ __launch_bounds__(256, 2) void gemm_qkv(const short* __restrict__ A,
                                                   const short* __restrict__ BT,
                                                   short* __restrict__ Qd, short* __restrict__ Kd,
                                                   short* __restrict__ VTb) {
    extern __shared__ __align__(16) short pool[];  // 34816 B
    short* sA = pool;          // [128][32]
    short* sB = pool + 4096;   // [128][32]
    short* sOut = pool;        // alias after barrier: [128][136]

    const int tid = threadIdx.x;
    const int w = tid >> 6, lane = tid & 63, quad = lane >> 4, l15 = lane & 15;
    const int wm = w >> 1, wn = w & 1;
    const int m0 = blockIdx.y * 128, n0 = blockIdx.x * 128;

    floatx4 acc[4][4];
#pragma unroll
    for (int i = 0; i < 4; i++)
#pragma unroll
        for (int j = 0; j < 4; j++) acc[i][j] = (floatx4){0.f, 0.f, 0.f, 0.f};

    for (int k0 = 0; k0 < 1024; k0 += 32) {
        __syncthreads();
#pragma unroll
        for (int i = 0; i < 2; ++i) {
            int c = i * 256 + tid;
            int r = c >> 2, kc = (c & 3) << 3;
            async16(A + (size_t)(m0 + r) * 1024 + k0 + kc, (char*)sA + c * 16);
            async16(BT + (size_t)(n0 + r) * 1024 + k0 + kc, (char*)sB + c * 16);
        }
        __syncthreads();
        short8 af[4], bf[4];
#pragma unroll
        for (int t = 0; t < 4; t++) {
            af[t] = *(const short8*)(sA + (wm * 64 + t * 16 + l15) * 32 + quad * 8);
            bf[t] = *(const short8*)(sB + (wn * 64 + t * 16 + l15) * 32 + quad * 8);
        }
#pragma unroll
        for (int tm = 0; tm < 4; tm++)
#pragma unroll
            for (int tn = 0; tn < 4; tn++) acc[tm][tn] = mfma16(af[tm], bf[tn], acc[tm][tn]);
    }

    __syncthreads();  // staging reads done; pool becomes sOut

    const int b = m0 >> 11, nnb = m0 & 2047;
    const bool isV = (n0 >= 2048);
    if (!isV) {
        // q scale folds softmax 1/8 and log2(e):  0.125 * 1.4426950408889634
        const float qs = (n0 < 1024) ? 0.18033688011112042f : 1.0f;
#pragma unroll
        for (int tn = 0; tn < 4; tn++) {
            const int d = tn * 16 + l15;
            const int colL = wn * 64 + tn * 16 + l15;
            const float inv = exp2f((float)(d >> 1) * -0.4152410118609203f);
#pragma unroll
            for (int tm = 0; tm < 4; tm++) {
                const int rowL = wm * 64 + tm * 16 + quad * 4;
#pragma unroll
                for (int i = 0; i < 4; i++) {
                    float v = acc[tm][tn][i];
                    float pv = __shfl_xor(v, 1);  // (even,odd) column pair partner
                    float ang = (float)(nnb + rowL + i) * inv;
                    float sn = __sinf(ang), cs = __cosf(ang);
                    float r = (d & 1) ? (pv * sn + v * cs) : (v * cs - pv * sn);
                    sOut[(rowL + i) * 136 + colL] = f2h(r * qs);
                }
            }
        }
        __syncthreads();
        short* dst0 = (n0 < 1024) ? Qd : Kd;
        const int hbase = (n0 & 1023) >> 6;
#pragma unroll
        for (int it = 0; it < 8; ++it) {
            int c = it * 256 + tid;
            int r = c >> 4, cg = (c & 15) * 8;
            int h = hbase + (cg >> 6), d = cg & 63;
            *(short8*)(dst0 + ((size_t)((b * 16 + h) * 2048 + nnb + r)) * 64 + d) =
                *(const short8*)(sOut + r * 136 + cg);
        }
    } else {
#pragma unroll
        for (int tn = 0; tn < 4; tn++) {
            const int colL = wn * 64 + tn * 16 + l15;
#pragma unroll
            for (int tm = 0; tm < 4; tm++) {
                const int rowL = wm * 64 + tm * 16 + quad * 4;
#pragma unroll
                for (int i = 0; i < 4; i++)
                    sOut[colL * 136 + rowL + i] = f2h(acc[tm][tn][i]);  // transposed tile
            }
        }
        __syncthreads();
        const int hbase = (n0 & 1023) >> 6;
#pragma unroll
        for (int it = 0; it < 8; ++it) {
            int c = it * 256 + tid;
            int ci = c >> 4, rg = (c & 15) * 8;
            int h = hbase + (ci >> 6), d = ci & 63;
            *(short8*)(VTb + ((size_t)((b * 16 + h) * 64 + d)) * 2048 + nnb + rg) =
                *(const short8*)(sOut + ci * 136 + rg);
        }
    }
}

// ---------------------------------------------------------------- out-proj GEMM (plain fp16)
__global__ __launch_bounds__(256, 2) void gemm_out(const short* __restrict__ A,
                                                   const short* __restrict__ BT,
                                                   float* __restrict__ Fout,
                                                   const float* __restrict__ bias) {
    __shared__ __align__(16) short sA[128 * 32];
    __shared__ __align__(16) short sB[128 * 32];
    const int tid = threadIdx.x;
    const int w = tid >> 6, lane = tid & 63, quad = lane >> 4, l15 = lane & 15;
    const int wm = w >> 1, wn = w & 1;
    const int m0 = blockIdx.y * 128, n0 = blockIdx.x * 128;

    floatx4 acc[4][4];
#pragma unroll
    for (int i = 0; i < 4; i++)
#pragma unroll
        for (int j = 0; j < 4; j++) acc[i][j] = (floatx4){0.f, 0.f, 0.f, 0.f};

    for (int k0 = 0; k0 < 1024; k0 += 32) {
        __syncthreads();
#pragma unroll
        for (int i = 0; i < 2; ++i) {
            int c = i * 256 + tid;
            int r = c >> 2, kc = (c & 3) << 3;
            async16(A + (size_t)(m0 + r) * 1024 + k0 + kc, (char*)sA + c * 16);
            async16(BT + (size_t)(n0 + r) * 1024 + k0 + kc, (char*)sB + c * 16);
        }
        __syncthreads();
        short8 af[4], bf[4];
#pragma unroll
        for (int t = 0; t < 4; t++) af[t] = *(const short8*)(sA + (wm * 64 + t * 16 + l15) * 32 + quad * 8);
#pragma unroll
        for (int t = 0; t < 4; t++) bf[t] = *(const short8*)(sB + (wn * 64 + t * 16 + l15) * 32 + quad * 8);
#pragma unroll
        for (int tm = 0; tm < 4; tm++)
#pragma unroll
            for (int tn = 0; tn < 4; tn++) acc[tm][tn] = mfma16(af[tm], bf[tn], acc[tm][tn]);
    }

    // fp32 stores: quad writes 4B x 16 lanes = 64B lines, coalesced
#pragma unroll
    for (int tn = 0; tn < 4; tn++) {
        const int col = n0 + wn * 64 + tn * 16 + l15;
        const float bb = bias[col];
#pragma unroll
        for (int tm = 0; tm < 4; tm++) {
            const int row0 = m0 + wm * 64 + tm * 16 + quad * 4;
#pragma unroll
            for (int i = 0; i < 4; i++) Fout[(size_t)(row0 + i) * 1024 + col] = acc[tm][tn][i] + bb;
        }
    }
}

// ---------------------------------------------------------------- attention (flash, fp16)
// Q (roped, pre-scaled by 0.125*log2e) [bh][n][64], K [bh][n][64], VT [bh][64][n]
// out [b][n][h*64+d] fp16.  Q-tile 64 rows/block (16/wave), KV-tile 128.
__global__ __launch_bounds__(256, 2) void attn_kernel(const short* __restrict__ Qg,
                                                      const short* __restrict__ Kg,
                                                      const short* __restrict__ VTg,
                                                      short* __restrict__ Og) {
    __shared__ __align__(16) short sKP[128 * 72];  // K [128][72] | P [64][136] | out [64][72]
    __shared__ __align__(16) short sVT[64 * 136];  // V^T tile

    const int tid = threadIdx.x;
    const int w = tid >> 6, lane = tid & 63, quad = lane >> 4, l15 = lane & 15;
    const int qt = blockIdx.x, bh = blockIdx.y;
    const int srcl = (l15 >> 2) << 4;  // lane holding row-(l15) stats (element l15&3)

    const short* Qp = Qg + (size_t)(bh * 2048 + qt * 64) * 64;
    const short* Kp = Kg + (size_t)bh * 2048 * 64;
    const short* Vp = VTg + (size_t)bh * 64 * 2048;

    short8 aq[2];
#pragma unroll
    for (int kh = 0; kh < 2; kh++)
        aq[kh] = *(const short8*)(Qp + (w * 16 + l15) * 64 + kh * 32 + quad * 8);

    floatx4 o[4];
#pragma unroll
    for (int i = 0; i < 4; i++) o[i] = (floatx4){0.f, 0.f, 0.f, 0.f};
    float m_run[4], l_run[4];
#pragma unroll
    for (int i = 0; i < 4; i++) { m_run[i] = -1e30f; l_run[i] = 0.f; }

    for (int kt = 0; kt < 16; ++kt) {
        const int n0 = kt * 128;
        __syncthreads();  // prior-iter P/VT reads done
#pragma unroll
        for (int i = 0; i < 4; ++i) {
            int c = i * 256 + tid;
            {
                int r = c >> 3, c8 = (c & 7) << 3;
                *(short8*)(sKP + r * 72 + c8) = *(const short8*)(Kp + (size_t)(n0 + r) * 64 + c8);
            }
            {
                int d = c >> 4, c16 = (c & 15) << 3;
                *(short8*)(sVT + d * 136 + c16) = *(const short8*)(Vp + (size_t)d * 2048 + n0 + c16);
            }
        }
        __syncthreads();

        floatx4 s[8];
#pragma unroll
        for (int tn = 0; tn < 8; tn++) {
            short8 b0 = *(const short8*)(sKP + (tn * 16 + l15) * 72 + quad * 8);
            short8 b1 = *(const short8*)(sKP + (tn * 16 + l15) * 72 + 32 + quad * 8);
            floatx4 z = (floatx4){0.f, 0.f, 0.f, 0.f};
            z = mfma16(aq[0], b0, z);
            z = mfma16(aq[1], b1, z);
            s[tn] = z;
        }
        __syncthreads();  // K reads done before P overwrites sKP

        // s is already in log2 units (scale folded into Q)
        float alpha[4];
#pragma unroll
        for (int i = 0; i < 4; i++) {
            float mx = s[0][i];
#pragma unroll
            for (int tn = 1; tn < 8; tn++) mx = fmaxf(mx, s[tn][i]);
#pragma unroll
            for (int off = 1; off < 16; off <<= 1) mx = fmaxf(mx, __shfl_xor(mx, off));
            float mn = fmaxf(m_run[i], mx);
            alpha[i] = exp2f(m_run[i] - mn);
            m_run[i] = mn;
        }
        float lsum[4] = {0.f, 0.f, 0.f, 0.f};
#pragma unroll
        for (int tn = 0; tn < 8; tn++)
#pragma unroll
            for (int i = 0; i < 4; i++) {
                float p = exp2f(s[tn][i] - m_run[i]);
                lsum[i] += p;
                sKP[(w * 16 + quad * 4 + i) * 136 + tn * 16 + l15] = f2h(p);
            }
#pragma unroll
        for (int i = 0; i < 4; i++) {
            float ls = lsum[i];
#pragma unroll
            for (int off = 1; off < 16; off <<= 1) ls += __shfl_xor(ls, off);
            l_run[i] = l_run[i] * alpha[i] + ls;
        }
        // broadcast alpha (rows quad*4+i) to col-indexed lanes (row = l15), register-only
        float t0 = __shfl(alpha[0], srcl), t1 = __shfl(alpha[1], srcl);
        float t2 = __shfl(alpha[2], srcl), t3 = __shfl(alpha[3], srcl);
        float a01 = (l15 & 1) ? t1 : t0, a23 = (l15 & 1) ? t3 : t2;
        float av = (l15 & 2) ? a23 : a01;
#pragma unroll
        for (int dt = 0; dt < 4; dt++) o[dt] *= av;
        __syncthreads();  // P visible before PV reads

#pragma unroll
        for (int nc = 0; nc < 4; nc++) {
            short8 pa[4];
#pragma unroll
            for (int dt = 0; dt < 4; dt++)
                pa[dt] = *(const short8*)(sVT + (dt * 16 + l15) * 136 + nc * 32 + quad * 8);
            short8 pb = *(const short8*)(sKP + (w * 16 + l15) * 136 + nc * 32 + quad * 8);
#pragma unroll
            for (int dt = 0; dt < 4; dt++) o[dt] = mfma16(pa[dt], pb, o[dt]);
        }
    }

    // broadcast l_run to col-indexed lanes
    float t0 = __shfl(l_run[0], srcl), t1 = __shfl(l_run[1], srcl);
    float t2 = __shfl(l_run[2], srcl), t3 = __shfl(l_run[3], srcl);
    float a01 = (l15 & 1) ? t1 : t0, a23 = (l15 & 1) ? t3 : t2;
    float linv = 1.0f / ((l15 & 2) ? a23 : a01);

    __syncthreads();  // last PV reads done; sKP becomes out-stage [64][72]
#pragma unroll
    for (int dt = 0; dt < 4; dt++) {
        short4v pk;
#pragma unroll
        for (int i = 0; i < 4; i++) pk[i] = f2h(o[dt][i] * linv);
        *(short4v*)(sKP + (w * 16 + l15) * 72 + dt * 16 + quad * 4) = pk;
    }
    __syncthreads();
    const int b = bh >> 4, h = bh & 15;
#pragma unroll
    for (int it = 0; it < 2; ++it) {
        int c = it * 256 + tid;
        int r = c >> 3, dg = (c & 7) * 8;
        *(short8*)(Og + (size_t)(b * 2048 + qt * 64 + r) * 1024 + h * 64 + dg) =
            *(const short8*)(sKP + r * 72 + dg);
    }
}

// ---------------------------------------------------------------- launch
extern "C" void kernel_launch(void* const* d_in, const int* in_sizes, int n_in, void* d_out,
                              int out_size, void* d_ws, size_t ws_size, hipStream_t stream) {
    const float* x = (const float*)d_in[0];
    const float* gamma = (const float*)d_in[1];
    const float* beta = (const float*)d_in[2];
    const float* w_qkv = (const float*)d_in[3];
    const float* w_out = (const float*)d_in[4];
    const float* b_out = (const float*)d_in[5];
    float* out = (float*)d_out;

    char* ws = (char*)d_ws;
    short* xh = (short*)ws;                   // [8192][1024] fp16; later reused as attn out
    short* wqkvT = (short*)(ws + 16777216);   // [3072][1024]
    short* woT = (short*)(ws + 23068672);     // [1024][1024]
    short* VTb = (short*)(ws + 25165824);     // [64][64][2048]
    // Q and K live in d_out (2 x 16.78 MB = d_out size exactly); final GEMM overwrites it.
    short* Qd = (short*)d_out;                // [64][2048][64]
    short* Kd = (short*)d_out + 8388608;      // [64][2048][64]

    ln_kernel<<<8192, 256, 0, stream>>>(x, gamma, beta, xh);
    tcast_h<<<dim3(96, 32), dim3(32, 8), 0, stream>>>(w_qkv, wqkvT, 1024, 3072);
    tcast_h<<<dim3(32, 32), dim3(32, 8), 0, stream>>>(w_out, woT, 1024, 1024);
    gemm_qkv<<<dim3(24, 64), 256, 34816, stream>>>(xh, wqkvT, Qd, Kd, VTb);
    attn_kernel<<<dim3(32, 64), 256, 0, stream>>>(Qd, Kd, VTb, xh);
    gemm_out<<<dim3(8, 64), 256, 0, stream>>>(xh, woT, out, b_out);
}

// Round 6
// 349.664 us; speedup vs baseline: 2.8390x; 1.1676x over previous
//
#include <hip/hip_runtime.h>
#include <hip/hip_fp16.h>

typedef __attribute__((ext_vector_type(8))) short short8;
typedef __attribute__((ext_vector_type(4))) short short4v;
typedef __attribute__((ext_vector_type(4))) float floatx4;
typedef _Float16 half8 __attribute__((ext_vector_type(8)));

static __device__ __forceinline__ short f2h(float f) {
    _Float16 h = (_Float16)f;
    return __builtin_bit_cast(short, h);
}

static __device__ __forceinline__ floatx4 mfma16(short8 a, short8 b, floatx4 c) {
    return __builtin_amdgcn_mfma_f32_16x16x32_f16(__builtin_bit_cast(half8, a),
                                                  __builtin_bit_cast(half8, b), c, 0, 0, 0);
}

static __device__ __forceinline__ void async16(const void* g, void* l) {
    __builtin_amdgcn_global_load_lds((const __attribute__((address_space(1))) void*)g,
                                     (__attribute__((address_space(3))) void*)l, 16, 0, 0);
}

// ---------------------------------------------------------------- LayerNorm -> fp16
__global__ __launch_bounds__(256) void ln_kernel(const float* __restrict__ x,
                                                 const float* __restrict__ gamma,
                                                 const float* __restrict__ beta,
                                                 short* __restrict__ xh) {
    __shared__ float red[8];
    const int row = blockIdx.x, tid = threadIdx.x;
    const int w = tid >> 6, lane = tid & 63;
    const float4 v = ((const float4*)(x + (size_t)row * 1024))[tid];
    float s = v.x + v.y + v.z + v.w;
    float ss = v.x * v.x + v.y * v.y + v.z * v.z + v.w * v.w;
#pragma unroll
    for (int off = 32; off; off >>= 1) {
        s += __shfl_xor(s, off);
        ss += __shfl_xor(ss, off);
    }
    if (lane == 0) { red[w] = s; red[4 + w] = ss; }
    __syncthreads();
    s = red[0] + red[1] + red[2] + red[3];
    ss = red[4] + red[5] + red[6] + red[7];
    const float mu = s * (1.f / 1024.f);
    const float rs = rsqrtf(ss * (1.f / 1024.f) - mu * mu + 1e-5f);
    const float4 g = ((const float4*)gamma)[tid];
    const float4 bt = ((const float4*)beta)[tid];
    short4v ph;
    ph[0] = f2h((v.x - mu) * rs * g.x + bt.x);
    ph[1] = f2h((v.y - mu) * rs * g.y + bt.y);
    ph[2] = f2h((v.z - mu) * rs * g.z + bt.z);
    ph[3] = f2h((v.w - mu) * rs * g.w + bt.w);
    *(short4v*)(xh + (size_t)row * 1024 + tid * 4) = ph;
}

// ------------------------------------------------- transpose + cast fp32 -> fp16
__global__ void tcast_h(const float* __restrict__ in, short* __restrict__ out, int R, int C) {
    __shared__ float t[32][33];
    const int bx = blockIdx.x * 32, by = blockIdx.y * 32;
    const int tx = threadIdx.x, ty = threadIdx.y;
#pragma unroll
    for (int i = 0; i < 32; i += 8) t[ty + i][tx] = in[(size_t)(by + ty + i) * C + bx + tx];
    __syncthreads();
#pragma unroll
    for (int i = 0; i < 32; i += 8) out[(size_t)(bx + ty + i) * R + by + tx] = f2h(t[tx][ty + i]);
}

// ---------------------------------------------------------------- QKV GEMM (plain fp16)
// C = A * BT^T. A: [8192][1024], BT: [3072][1024].
// Epilogue: RoPE on q/k; Q scaled by 0.125*log2(e) (log2-domain softmax downstream);
// Q/K -> [bh][n][64]; V transposed -> [bh][d][n]. LDS-staged coalesced stores.
// (byte-identical to the R4 passing version)
__global__ __launch_bounds__(256, 2) void gemm_qkv(const short* __restrict__ A,
                                                   const short* __restrict__ BT,
                                                   short* __restrict__ Qd, short* __restrict__ Kd,
                                                   short* __restrict__ VTb) {
    extern __shared__ __align__(16) short pool[];  // 34816 B
    short* sA = pool;          // [128][32]
    short* sB = pool + 4096;   // [128][32]
    short* sOut = pool;        // alias after barrier: [128][136]

    const int tid = threadIdx.x;
    const int w = tid >> 6, lane = tid & 63, quad = lane >> 4, l15 = lane & 15;
    const int wm = w >> 1, wn = w & 1;
    const int m0 = blockIdx.y * 128, n0 = blockIdx.x * 128;

    floatx4 acc[4][4];
#pragma unroll
    for (int i = 0; i < 4; i++)
#pragma unroll
        for (int j = 0; j < 4; j++) acc[i][j] = (floatx4){0.f, 0.f, 0.f, 0.f};

    for (int k0 = 0; k0 < 1024; k0 += 32) {
        __syncthreads();
#pragma unroll
        for (int i = 0; i < 2; ++i) {
            int c = i * 256 + tid;
            int r = c >> 2, kc = (c & 3) << 3;
            async16(A + (size_t)(m0 + r) * 1024 + k0 + kc, (char*)sA + c * 16);
            async16(BT + (size_t)(n0 + r) * 1024 + k0 + kc, (char*)sB + c * 16);
        }
        __syncthreads();
        short8 af[4], bf[4];
#pragma unroll
        for (int t = 0; t < 4; t++) {
            af[t] = *(const short8*)(sA + (wm * 64 + t * 16 + l15) * 32 + quad * 8);
            bf[t] = *(const short8*)(sB + (wn * 64 + t * 16 + l15) * 32 + quad * 8);
        }
#pragma unroll
        for (int tm = 0; tm < 4; tm++)
#pragma unroll
            for (int tn = 0; tn < 4; tn++) acc[tm][tn] = mfma16(af[tm], bf[tn], acc[tm][tn]);
    }

    __syncthreads();  // staging reads done; pool becomes sOut

    const int b = m0 >> 11, nnb = m0 & 2047;
    const bool isV = (n0 >= 2048);
    if (!isV) {
        // q scale folds softmax 1/8 and log2(e):  0.125 * 1.4426950408889634
        const float qs = (n0 < 1024) ? 0.18033688011112042f : 1.0f;
#pragma unroll
        for (int tn = 0; tn < 4; tn++) {
            const int d = tn * 16 + l15;
            const int colL = wn * 64 + tn * 16 + l15;
            const float inv = exp2f((float)(d >> 1) * -0.4152410118609203f);
#pragma unroll
            for (int tm = 0; tm < 4; tm++) {
                const int rowL = wm * 64 + tm * 16 + quad * 4;
#pragma unroll
                for (int i = 0; i < 4; i++) {
                    float v = acc[tm][tn][i];
                    float pv = __shfl_xor(v, 1);  // (even,odd) column pair partner
                    float ang = (float)(nnb + rowL + i) * inv;
                    float sn = __sinf(ang), cs = __cosf(ang);
                    float r = (d & 1) ? (pv * sn + v * cs) : (v * cs - pv * sn);
                    sOut[(rowL + i) * 136 + colL] = f2h(r * qs);
                }
            }
        }
        __syncthreads();
        short* dst0 = (n0 < 1024) ? Qd : Kd;
        const int hbase = (n0 & 1023) >> 6;
#pragma unroll
        for (int it = 0; it < 8; ++it) {
            int c = it * 256 + tid;
            int r = c >> 4, cg = (c & 15) * 8;
            int h = hbase + (cg >> 6), d = cg & 63;
            *(short8*)(dst0 + ((size_t)((b * 16 + h) * 2048 + nnb + r)) * 64 + d) =
                *(const short8*)(sOut + r * 136 + cg);
        }
    } else {
#pragma unroll
        for (int tn = 0; tn < 4; tn++) {
            const int colL = wn * 64 + tn * 16 + l15;
#pragma unroll
            for (int tm = 0; tm < 4; tm++) {
                const int rowL = wm * 64 + tm * 16 + quad * 4;
#pragma unroll
                for (int i = 0; i < 4; i++)
                    sOut[colL * 136 + rowL + i] = f2h(acc[tm][tn][i]);  // transposed tile
            }
        }
        __syncthreads();
        const int hbase = (n0 & 1023) >> 6;
#pragma unroll
        for (int it = 0; it < 8; ++it) {
            int c = it * 256 + tid;
            int ci = c >> 4, rg = (c & 15) * 8;
            int h = hbase + (ci >> 6), d = ci & 63;
            *(short8*)(VTb + ((size_t)((b * 16 + h) * 64 + d)) * 2048 + nnb + rg) =
                *(const short8*)(sOut + ci * 136 + rg);
        }
    }
}

// ---------------------------------------------------------------- out-proj GEMM (plain fp16)
__global__ __launch_bounds__(256, 2) void gemm_out(const short* __restrict__ A,
                                                   const short* __restrict__ BT,
                                                   float* __restrict__ Fout,
                                                   const float* __restrict__ bias) {
    __shared__ __align__(16) short sA[128 * 32];
    __shared__ __align__(16) short sB[128 * 32];
    const int tid = threadIdx.x;
    const int w = tid >> 6, lane = tid & 63, quad = lane >> 4, l15 = lane & 15;
    const int wm = w >> 1, wn = w & 1;
    const int m0 = blockIdx.y * 128, n0 = blockIdx.x * 128;

    floatx4 acc[4][4];
#pragma unroll
    for (int i = 0; i < 4; i++)
#pragma unroll
        for (int j = 0; j < 4; j++) acc[i][j] = (floatx4){0.f, 0.f, 0.f, 0.f};

    for (int k0 = 0; k0 < 1024; k0 += 32) {
        __syncthreads();
#pragma unroll
        for (int i = 0; i < 2; ++i) {
            int c = i * 256 + tid;
            int r = c >> 2, kc = (c & 3) << 3;
            async16(A + (size_t)(m0 + r) * 1024 + k0 + kc, (char*)sA + c * 16);
            async16(BT + (size_t)(n0 + r) * 1024 + k0 + kc, (char*)sB + c * 16);
        }
        __syncthreads();
        short8 af[4], bf[4];
#pragma unroll
        for (int t = 0; t < 4; t++) af[t] = *(const short8*)(sA + (wm * 64 + t * 16 + l15) * 32 + quad * 8);
#pragma unroll
        for (int t = 0; t < 4; t++) bf[t] = *(const short8*)(sB + (wn * 64 + t * 16 + l15) * 32 + quad * 8);
#pragma unroll
        for (int tm = 0; tm < 4; tm++)
#pragma unroll
            for (int tn = 0; tn < 4; tn++) acc[tm][tn] = mfma16(af[tm], bf[tn], acc[tm][tn]);
    }

#pragma unroll
    for (int tn = 0; tn < 4; tn++) {
        const int col = n0 + wn * 64 + tn * 16 + l15;
        const float bb = bias[col];
#pragma unroll
        for (int tm = 0; tm < 4; tm++) {
            const int row0 = m0 + wm * 64 + tm * 16 + quad * 4;
#pragma unroll
            for (int i = 0; i < 4; i++) Fout[(size_t)(row0 + i) * 1024 + col] = acc[tm][tn][i] + bb;
        }
    }
}

// ---------------------------------------------------------------- attention (flash, fp16)
// Q (roped, pre-scaled by 0.125*log2e) [bh][n][64], K (roped) [bh][n][64], VT [bh][64][n]
// out [b][n][h*64+d] fp16.  Q-tile 64 rows/block (16/wave), KV-tile 128.
// No-max softmax: p = exp2(s) (s in log2 units, bounded); row-sums l via ones-MFMA in PV.
// R4-proven mechanics: padded strides, VGPR-round-trip staging, barriers on every
// cross-lane LDS hand-off.
__global__ __launch_bounds__(256, 2) void attn_kernel(const short* __restrict__ Qg,
                                                      const short* __restrict__ Kg,
                                                      const short* __restrict__ VTg,
                                                      short* __restrict__ Og) {
    __shared__ __align__(16) short sK[128 * 72];   // K tile; reused as out-stage [64][72]
    __shared__ __align__(16) short sVT[64 * 132];  // V^T tile
    __shared__ __align__(16) short sP[64 * 132];   // P tile

    const int tid = threadIdx.x;
    const int w = tid >> 6, lane = tid & 63, quad = lane >> 4, l15 = lane & 15;
    const int qt = blockIdx.x, bh = blockIdx.y;

    const short* Qp = Qg + (size_t)(bh * 2048 + qt * 64) * 64;
    const short* Kp = Kg + (size_t)bh * 2048 * 64;
    const short* Vp = VTg + (size_t)bh * 64 * 2048;

    short8 aq[2];
#pragma unroll
    for (int kh = 0; kh < 2; kh++)
        aq[kh] = *(const short8*)(Qp + (w * 16 + l15) * 64 + kh * 32 + quad * 8);

    short8 ones;
#pragma unroll
    for (int j = 0; j < 8; j++) ones[j] = 0x3C00;  // 1.0h

    floatx4 o4[4], ol;
#pragma unroll
    for (int i = 0; i < 4; i++) o4[i] = (floatx4){0.f, 0.f, 0.f, 0.f};
    ol = (floatx4){0.f, 0.f, 0.f, 0.f};

    for (int kt = 0; kt < 16; ++kt) {
        const int n0 = kt * 128;
        __syncthreads();  // prior-iter sVT/sP reads done before restaging
#pragma unroll
        for (int i = 0; i < 4; ++i) {
            int c = i * 256 + tid;
            {
                int r = c >> 3, c8 = (c & 7) << 3;
                *(short8*)(sK + r * 72 + c8) = *(const short8*)(Kp + (size_t)(n0 + r) * 64 + c8);
            }
            {
                int d = c >> 4, c16 = (c & 15) << 3;
                *(short8*)(sVT + d * 132 + c16) = *(const short8*)(Vp + (size_t)d * 2048 + n0 + c16);
            }
        }
        __syncthreads();

        // QK^T -> p = exp2(s) -> P store (own buffer, stride 132)
#pragma unroll
        for (int tn = 0; tn < 8; tn++) {
            short8 b0 = *(const short8*)(sK + (tn * 16 + l15) * 72 + quad * 8);
            short8 b1 = *(const short8*)(sK + (tn * 16 + l15) * 72 + 32 + quad * 8);
            floatx4 z = (floatx4){0.f, 0.f, 0.f, 0.f};
            z = mfma16(aq[0], b0, z);
            z = mfma16(aq[1], b1, z);
#pragma unroll
            for (int i = 0; i < 4; i++)
                sP[(w * 16 + quad * 4 + i) * 132 + tn * 16 + l15] = f2h(exp2f(z[i]));
        }
        __syncthreads();  // P (cross-lane) visible before PV reads

        // PV: O^T += V^T * P^T ; l via ones fragment
#pragma unroll
        for (int nc = 0; nc < 4; nc++) {
            short8 pb = *(const short8*)(sP + (w * 16 + l15) * 132 + nc * 32 + quad * 8);
            short8 pa[4];
#pragma unroll
            for (int dt = 0; dt < 4; dt++)
                pa[dt] = *(const short8*)(sVT + (dt * 16 + l15) * 132 + nc * 32 + quad * 8);
#pragma unroll
            for (int dt = 0; dt < 4; dt++) o4[dt] = mfma16(pa[dt], pb, o4[dt]);
            ol = mfma16(ones, pb, ol);
        }
    }

    const float linv = 1.0f / ol[0];  // l[q = w*16+l15]; all 4 acc rows equal

    __syncthreads();  // all sK reads long done; reuse as out-stage [64][72]
    short* sOut = sK;
#pragma unroll
    for (int dt = 0; dt < 4; dt++) {
        short4v pk;
#pragma unroll
        for (int i = 0; i < 4; i++) pk[i] = f2h(o4[dt][i] * linv);
        *(short4v*)(sOut + (w * 16 + l15) * 72 + dt * 16 + quad * 4) = pk;
    }
    __syncthreads();
    const int b = bh >> 4, h = bh & 15;
#pragma unroll
    for (int it = 0; it < 2; ++it) {
        int c = it * 256 + tid;
        int r = c >> 3, dg = (c & 7) * 8;
        *(short8*)(Og + (size_t)(b * 2048 + qt * 64 + r) * 1024 + h * 64 + dg) =
            *(const short8*)(sOut + r * 72 + dg);
    }
}

// ---------------------------------------------------------------- launch
extern "C" void kernel_launch(void* const* d_in, const int* in_sizes, int n_in, void* d_out,
                              int out_size, void* d_ws, size_t ws_size, hipStream_t stream) {
    const float* x = (const float*)d_in[0];
    const float* gamma = (const float*)d_in[1];
    const float* beta = (const float*)d_in[2];
    const float* w_qkv = (const float*)d_in[3];
    const float* w_out = (const float*)d_in[4];
    const float* b_out = (const float*)d_in[5];
    float* out = (float*)d_out;

    char* ws = (char*)d_ws;
    short* xh = (short*)ws;                   // [8192][1024] fp16; later reused as attn out
    short* wqkvT = (short*)(ws + 16777216);   // [3072][1024]
    short* woT = (short*)(ws + 23068672);     // [1024][1024]
    short* VTb = (short*)(ws + 25165824);     // [64][64][2048]
    // Q and K live in d_out (2 x 16.78 MB); final GEMM overwrites it.
    short* Qd = (short*)d_out;                // [64][2048][64] (roped, scaled)
    short* Kd = (short*)d_out + 8388608;      // [64][2048][64] (roped)

    ln_kernel<<<8192, 256, 0, stream>>>(x, gamma, beta, xh);
    tcast_h<<<dim3(96, 32), dim3(32, 8), 0, stream>>>(w_qkv, wqkvT, 1024, 3072);
    tcast_h<<<dim3(32, 32), dim3(32, 8), 0, stream>>>(w_out, woT, 1024, 1024);
    gemm_qkv<<<dim3(24, 64), 256, 34816, stream>>>(xh, wqkvT, Qd, Kd, VTb);
    attn_kernel<<<dim3(32, 64), 256, 0, stream>>>(Qd, Kd, VTb, xh);
    gemm_out<<<dim3(8, 64), 256, 0, stream>>>(xh, woT, out, b_out);
}